// Round 10
// baseline (177.898 us; speedup 1.0000x reference)
//
#include <hip/hip_runtime.h>
#include <math.h>

// HDCFactMemory:
//   out = x + r_gate[b,t] * K[d] * sign(S[b,t,d]) * sign(x[b,t,d])
//   K[d] = sign(role_write[d])*sign(role_read[d])   (factored, exact)
//   S[b,t,d] = sum_{t'<=t} sign(x[b,t',d]) * w_gate[b,t']
// Sign-determining math in f64 (np-f64 reference; validated R2-R9, absmax
// pinned at bf16 floor 0.015625).
//
// R10 = R9 INSTRUMENTATION ROUND: final_kernel launched 3x (idempotent:
// rewrites identical values). K3_warm = (dur - 88.8)/2. Decision rule:
//   K3_warm < 28us -> attack K12 next; >= 35us -> attack K3 internals.

#define T_LEN 4096
#define D_LEN 4096
#define TC 32              // rows per chunk
#define NC (T_LEN / TC)    // 128 chunks per batch
#define D4 (D_LEN / 4)     // 1024 float4 (and code-bytes) per row

typedef float nfloat4 __attribute__((ext_vector_type(4)));

__device__ __forceinline__ float fsgn(float v) {
    return (v > 0.f) ? 1.f : ((v < 0.f) ? -1.f : 0.f);
}
__device__ __forceinline__ double dsgn(double v) {
    return (v > 0.) ? 1. : ((v < 0.) ? -1. : 0.);
}
__device__ __forceinline__ unsigned scode(float v) {   // 0:neg 1:zero 2:pos
    return (v > 0.f) ? 2u : ((v < 0.f) ? 0u : 1u);
}

// ---- K12: per-chunk gates + partials (codes via LDS, no global round-trip)
__global__ __launch_bounds__(1024) void gates_partial_kernel(
    const float* __restrict__ x,
    const float* __restrict__ wg_w, const float* __restrict__ wg_b,
    const float* __restrict__ rg_w, const float* __restrict__ rg_b,
    double* __restrict__ wgate, double* __restrict__ rgate,
    double* __restrict__ partial)
{
    const int c = blockIdx.x;
    const int b = blockIdx.y;
    const int tid = threadIdx.x;

    __shared__ unsigned char codes[TC][D4];   // 32 KB
    __shared__ double wg_s[TC];
    __shared__ double rg_s[TC];

    // ---- phase A: gate dots (32 threads per row) + code pack into LDS ----
    const int r  = tid >> 5;          // row in chunk [0,32)
    const int k0 = tid & 31;          // 32 threads stride the row
    const float4* xr = (const float4*)(x + ((size_t)b * T_LEN + (size_t)c * TC + r) * D_LEN);
    const float4* w4 = (const float4*)wg_w;
    const float4* g4 = (const float4*)rg_w;

    double dw = 0., dg = 0.;
    #pragma unroll 4
    for (int j = 0; j < 32; ++j) {
        const int idx = k0 + j * 32;
        float4 v = xr[idx];
        float4 a = w4[idx];
        float4 g = g4[idx];
        dw += (double)v.x * a.x + (double)v.y * a.y
            + (double)v.z * a.z + (double)v.w * a.w;
        dg += (double)v.x * g.x + (double)v.y * g.y
            + (double)v.z * g.z + (double)v.w * g.w;
        codes[r][idx] = (unsigned char)(scode(v.x) | (scode(v.y) << 2)
                                      | (scode(v.z) << 4) | (scode(v.w) << 6));
    }
    #pragma unroll
    for (int off = 16; off >= 1; off >>= 1) {
        dw += __shfl_down(dw, off, 32);
        dg += __shfl_down(dg, off, 32);
    }
    if (k0 == 0) {
        wg_s[r] = 1. / (1. + exp(-(dw + (double)wg_b[0])));
        rg_s[r] = 1. / (1. + exp(-(dg + (double)rg_b[0])));
    }
    __syncthreads();

    // export gates for K3
    if (tid < TC) {
        const int row = b * T_LEN + c * TC + tid;
        wgate[row] = wg_s[tid];
        rgate[row] = rg_s[tid];
    }

    // ---- phase B: chunk partial per byte-column (thread = one float4 col) --
    double a0 = 0., a1 = 0., a2 = 0., a3 = 0.;
    #pragma unroll 8
    for (int t = 0; t < TC; ++t) {
        unsigned code = codes[t][tid];
        double w = wg_s[t];
        a0 += (double)((int)( code       & 3u) - 1) * w;
        a1 += (double)((int)((code >> 2) & 3u) - 1) * w;
        a2 += (double)((int)((code >> 4) & 3u) - 1) * w;
        a3 += (double)((int)((code >> 6) & 3u) - 1) * w;
    }
    double* rec = partial + ((size_t)(b * NC + c)) * D_LEN + tid * 4;
    rec[0] = a0; rec[1] = a1; rec[2] = a2; rec[3] = a3;
}

// ---- K2b: exclusive prefix over chunks per column ----
__global__ __launch_bounds__(256) void prefix_kernel(
    const double* __restrict__ partial, double* __restrict__ prefix)
{
    const int m = blockIdx.x * 256 + threadIdx.x;   // column in [0, 4096)
    const int b = blockIdx.y;
    double s = 0.;
    for (int c = 0; c < NC; ++c) {
        size_t idx = ((size_t)(b * NC + c)) * D_LEN + m;
        double v = partial[idx];
        prefix[idx] = s;
        s += v;
    }
}

// ---- K3: in-chunk sequential f64 rescan + f32 output (NT stores) ----
__global__ __launch_bounds__(256) void final_kernel(
    const float* __restrict__ x,
    const double* __restrict__ wgate, const double* __restrict__ rgate,
    const float* __restrict__ role_w, const float* __restrict__ role_r,
    const double* __restrict__ prefix,
    float* __restrict__ out)
{
    const int b = blockIdx.z;
    const int c = blockIdx.y;
    const int d4 = blockIdx.x * 256 + threadIdx.x;

    __shared__ double wsm[TC];
    __shared__ float rsm[TC];
    if (threadIdx.x < TC) {
        wsm[threadIdx.x] = wgate[b * T_LEN + c * TC + threadIdx.x];
        rsm[threadIdx.x] = (float)rgate[b * T_LEN + c * TC + threadIdx.x];
    }
    __syncthreads();

    float4 rw = ((const float4*)role_w)[d4];
    float4 rr = ((const float4*)role_r)[d4];
    const float kx = fsgn(rw.x) * fsgn(rr.x);
    const float ky = fsgn(rw.y) * fsgn(rr.y);
    const float kz = fsgn(rw.z) * fsgn(rr.z);
    const float kw = fsgn(rw.w) * fsgn(rr.w);

    const double* p = prefix + ((size_t)(b * NC + c)) * D_LEN + d4 * 4;
    double ax = p[0], ay = p[1], az = p[2], aw = p[3];

    const float4* x4 = (const float4*)x;
    nfloat4* o4 = (nfloat4*)out;
    const size_t slab = ((size_t)b * T_LEN + (size_t)c * TC) * D4 + d4;

    #pragma unroll 4
    for (int i = 0; i < TC; ++i) {
        float4 v = x4[slab + (size_t)i * D4];
        double w = wsm[i];
        float rf = rsm[i];
        float sx = fsgn(v.x), sy = fsgn(v.y), sz = fsgn(v.z), sw2 = fsgn(v.w);
        ax += (double)sx * w; ay += (double)sy * w;
        az += (double)sz * w; aw += (double)sw2 * w;
        nfloat4 o;
        o.x = v.x + rf * kx * (float)dsgn(ax) * sx;
        o.y = v.y + rf * ky * (float)dsgn(ay) * sy;
        o.z = v.z + rf * kz * (float)dsgn(az) * sz;
        o.w = v.w + rf * kw * (float)dsgn(aw) * sw2;
        __builtin_nontemporal_store(o, &o4[slab + (size_t)i * D4]);
    }
}

extern "C" void kernel_launch(void* const* d_in, const int* in_sizes, int n_in,
                              void* d_out, int out_size, void* d_ws, size_t ws_size,
                              hipStream_t stream) {
    const float* x      = (const float*)d_in[0];
    const float* role_w = (const float*)d_in[1];
    const float* role_r = (const float*)d_in[2];
    const float* wg_w   = (const float*)d_in[3];
    const float* wg_b   = (const float*)d_in[4];
    const float* rg_w   = (const float*)d_in[5];
    const float* rg_b   = (const float*)d_in[6];
    float* out = (float*)d_out;

    const int B = in_sizes[0] / (T_LEN * D_LEN);   // = 2
    const int BT = B * T_LEN;

    // ws layout (f64): wgate[BT], rgate[BT], partial[B*NC*D], prefix[same]
    double* wgate   = (double*)d_ws;
    double* rgate   = wgate + BT;
    double* partial = rgate + BT;
    double* prefix  = partial + (size_t)B * NC * D_LEN;   // total ~17 MB

    dim3 g12(NC, B);               // (128, 2)
    gates_partial_kernel<<<g12, 1024, 0, stream>>>(
        x, wg_w, wg_b, rg_w, rg_b, wgate, rgate, partial);

    dim3 g2b(D_LEN / 256, B);      // (16, 2)
    prefix_kernel<<<g2b, 256, 0, stream>>>(partial, prefix);

    dim3 g3(D4 / 256, NC, B);      // (4, 128, 2)
    // INSTRUMENTATION: K3 launched 3x (idempotent). K3_warm = (dur-88.8)/2.
    final_kernel<<<g3, 256, 0, stream>>>(
        x, wgate, rgate, role_w, role_r, prefix, out);
    final_kernel<<<g3, 256, 0, stream>>>(
        x, wgate, rgate, role_w, role_r, prefix, out);
    final_kernel<<<g3, 256, 0, stream>>>(
        x, wgate, rgate, role_w, role_r, prefix, out);
}

// Round 11
// 122.270 us; speedup vs baseline: 1.4550x; 1.4550x over previous
//
#include <hip/hip_runtime.h>
#include <math.h>

// HDCFactMemory:
//   out = x + r_gate[b,t] * K[d] * sign(S[b,t,d]) * sign(x[b,t,d])
//   K[d] = sign(role_write[d])*sign(role_read[d])   (factored, exact)
//   S[b,t,d] = sum_{t'<=t} sign(x[b,t',d]) * w_gate[b,t']
// Sign-determining math in f64 (np-f64 reference; absmax pinned at 0.015625).
//
// R11 (post R10 instrumentation: K3_warm=44.5us ~ stream floor; slack is
// K12 occupancy + K2b serial-latency):
//   K12 TC=16 -> 512 blocks (2/CU), 1 wave per gate-dot row, 16KB LDS codes
//   K2b sectioned parallel prefix: 8 thr/col, 32-chunk sections, shfl scan
//   K3  unchanged (NC=256)

#define T_LEN 4096
#define D_LEN 4096
#define TC 16              // rows per chunk
#define NC (T_LEN / TC)    // 256 chunks per batch
#define D4 (D_LEN / 4)     // 1024 float4 (and code-bytes) per row
#define NSEC 8             // prefix sections per column
#define SEC (NC / NSEC)    // 32 chunks per section

typedef float nfloat4 __attribute__((ext_vector_type(4)));

__device__ __forceinline__ float fsgn(float v) {
    return (v > 0.f) ? 1.f : ((v < 0.f) ? -1.f : 0.f);
}
__device__ __forceinline__ double dsgn(double v) {
    return (v > 0.) ? 1. : ((v < 0.) ? -1. : 0.);
}
__device__ __forceinline__ unsigned scode(float v) {   // 0:neg 1:zero 2:pos
    return (v > 0.f) ? 2u : ((v < 0.f) ? 0u : 1u);
}

// ---- K12: per-chunk gates (1 wave/row) + partials via 16KB LDS codes ----
__global__ __launch_bounds__(1024) void gates_partial_kernel(
    const float* __restrict__ x,
    const float* __restrict__ wg_w, const float* __restrict__ wg_b,
    const float* __restrict__ rg_w, const float* __restrict__ rg_b,
    double* __restrict__ wgate, double* __restrict__ rgate,
    double* __restrict__ partial)
{
    const int c = blockIdx.x;
    const int b = blockIdx.y;
    const int tid = threadIdx.x;

    __shared__ unsigned char codes[TC][D4];   // 16 KB
    __shared__ double wg_s[TC];
    __shared__ double rg_s[TC];

    // ---- phase A: gate dots (64 threads = 1 wave per row) + code pack ----
    const int r    = tid >> 6;        // row in chunk [0,16)
    const int lane = tid & 63;
    const float4* xr = (const float4*)(x + ((size_t)b * T_LEN + (size_t)c * TC + r) * D_LEN);
    const float4* w4 = (const float4*)wg_w;
    const float4* g4 = (const float4*)rg_w;

    double dw = 0., dg = 0.;
    #pragma unroll 4
    for (int j = 0; j < D4 / 64; ++j) {   // 16 iters, wave reads 1KB/instr
        const int idx = lane + j * 64;
        float4 v = xr[idx];
        float4 a = w4[idx];
        float4 g = g4[idx];
        dw += (double)v.x * a.x + (double)v.y * a.y
            + (double)v.z * a.z + (double)v.w * a.w;
        dg += (double)v.x * g.x + (double)v.y * g.y
            + (double)v.z * g.z + (double)v.w * g.w;
        codes[r][idx] = (unsigned char)(scode(v.x) | (scode(v.y) << 2)
                                      | (scode(v.z) << 4) | (scode(v.w) << 6));
    }
    #pragma unroll
    for (int off = 32; off >= 1; off >>= 1) {
        dw += __shfl_down(dw, off);
        dg += __shfl_down(dg, off);
    }
    if (lane == 0) {
        wg_s[r] = 1. / (1. + exp(-(dw + (double)wg_b[0])));
        rg_s[r] = 1. / (1. + exp(-(dg + (double)rg_b[0])));
    }
    __syncthreads();

    // export gates for K3
    if (tid < TC) {
        const int row = b * T_LEN + c * TC + tid;
        wgate[row] = wg_s[tid];
        rgate[row] = rg_s[tid];
    }

    // ---- phase B: chunk partial per byte-column ----
    double a0 = 0., a1 = 0., a2 = 0., a3 = 0.;
    #pragma unroll 8
    for (int t = 0; t < TC; ++t) {
        unsigned code = codes[t][tid];
        double w = wg_s[t];
        a0 += (double)((int)( code       & 3u) - 1) * w;
        a1 += (double)((int)((code >> 2) & 3u) - 1) * w;
        a2 += (double)((int)((code >> 4) & 3u) - 1) * w;
        a3 += (double)((int)((code >> 6) & 3u) - 1) * w;
    }
    double* rec = partial + ((size_t)(b * NC + c)) * D_LEN + tid * 4;
    rec[0] = a0; rec[1] = a1; rec[2] = a2; rec[3] = a3;
}

// ---- K2b: sectioned parallel exclusive prefix over chunks ----
// 8 threads per column; section = 32 chunks. Section sums -> 8-lane
// shfl exclusive scan -> rewalk writing prefixes. Serial chain 256 -> 32.
__global__ __launch_bounds__(1024) void prefix_kernel(
    const double* __restrict__ partial, double* __restrict__ prefix)
{
    const int tid  = threadIdx.x;
    const int col8 = tid >> 3;            // 128 columns per block
    const int sec  = tid & 7;
    const int g    = blockIdx.x * 128 + col8;   // global column in [0, B*D)
    const int b    = g >> 12;             // /4096
    const int m    = g & 4095;

    // section sum (loads address-independent -> pipelined)
    double s = 0.;
    #pragma unroll 8
    for (int k = 0; k < SEC; ++k) {
        const int cc = sec * SEC + k;
        s += partial[((size_t)(b * NC + cc)) * D_LEN + m];
    }
    // inclusive 8-lane scan, then shift for exclusive
    double inc = s;
    #pragma unroll
    for (int off = 1; off < NSEC; off <<= 1) {
        double n = __shfl_up(inc, off, NSEC);
        if (sec >= off) inc += n;
    }
    double run = __shfl_up(inc, 1, NSEC);
    if (sec == 0) run = 0.;
    // rewalk: write exclusive prefix per chunk
    #pragma unroll 8
    for (int k = 0; k < SEC; ++k) {
        const int cc = sec * SEC + k;
        const size_t idx = ((size_t)(b * NC + cc)) * D_LEN + m;
        double v = partial[idx];
        prefix[idx] = run;
        run += v;
    }
}

// ---- K3: in-chunk sequential f64 rescan + f32 output (NT stores) ----
__global__ __launch_bounds__(256) void final_kernel(
    const float* __restrict__ x,
    const double* __restrict__ wgate, const double* __restrict__ rgate,
    const float* __restrict__ role_w, const float* __restrict__ role_r,
    const double* __restrict__ prefix,
    float* __restrict__ out)
{
    const int b = blockIdx.z;
    const int c = blockIdx.y;
    const int d4 = blockIdx.x * 256 + threadIdx.x;

    __shared__ double wsm[TC];
    __shared__ float rsm[TC];
    if (threadIdx.x < TC) {
        wsm[threadIdx.x] = wgate[b * T_LEN + c * TC + threadIdx.x];
        rsm[threadIdx.x] = (float)rgate[b * T_LEN + c * TC + threadIdx.x];
    }
    __syncthreads();

    float4 rw = ((const float4*)role_w)[d4];
    float4 rr = ((const float4*)role_r)[d4];
    const float kx = fsgn(rw.x) * fsgn(rr.x);
    const float ky = fsgn(rw.y) * fsgn(rr.y);
    const float kz = fsgn(rw.z) * fsgn(rr.z);
    const float kw = fsgn(rw.w) * fsgn(rr.w);

    const double* p = prefix + ((size_t)(b * NC + c)) * D_LEN + d4 * 4;
    double ax = p[0], ay = p[1], az = p[2], aw = p[3];

    const float4* x4 = (const float4*)x;
    nfloat4* o4 = (nfloat4*)out;
    const size_t slab = ((size_t)b * T_LEN + (size_t)c * TC) * D4 + d4;

    #pragma unroll 4
    for (int i = 0; i < TC; ++i) {
        float4 v = x4[slab + (size_t)i * D4];
        double w = wsm[i];
        float rf = rsm[i];
        float sx = fsgn(v.x), sy = fsgn(v.y), sz = fsgn(v.z), sw2 = fsgn(v.w);
        ax += (double)sx * w; ay += (double)sy * w;
        az += (double)sz * w; aw += (double)sw2 * w;
        nfloat4 o;
        o.x = v.x + rf * kx * (float)dsgn(ax) * sx;
        o.y = v.y + rf * ky * (float)dsgn(ay) * sy;
        o.z = v.z + rf * kz * (float)dsgn(az) * sz;
        o.w = v.w + rf * kw * (float)dsgn(aw) * sw2;
        __builtin_nontemporal_store(o, &o4[slab + (size_t)i * D4]);
    }
}

extern "C" void kernel_launch(void* const* d_in, const int* in_sizes, int n_in,
                              void* d_out, int out_size, void* d_ws, size_t ws_size,
                              hipStream_t stream) {
    const float* x      = (const float*)d_in[0];
    const float* role_w = (const float*)d_in[1];
    const float* role_r = (const float*)d_in[2];
    const float* wg_w   = (const float*)d_in[3];
    const float* wg_b   = (const float*)d_in[4];
    const float* rg_w   = (const float*)d_in[5];
    const float* rg_b   = (const float*)d_in[6];
    float* out = (float*)d_out;

    const int B = in_sizes[0] / (T_LEN * D_LEN);   // = 2
    const int BT = B * T_LEN;

    // ws layout (f64): wgate[BT], rgate[BT], partial[B*NC*D], prefix[same]
    double* wgate   = (double*)d_ws;
    double* rgate   = wgate + BT;
    double* partial = rgate + BT;
    double* prefix  = partial + (size_t)B * NC * D_LEN;   // total ~34 MB

    dim3 g12(NC, B);               // (256, 2) = 512 blocks
    gates_partial_kernel<<<g12, 1024, 0, stream>>>(
        x, wg_w, wg_b, rg_w, rg_b, wgate, rgate, partial);

    const int ncols = B * D_LEN;   // 8192 columns, 128 per block
    prefix_kernel<<<ncols / 128, 1024, 0, stream>>>(partial, prefix);

    dim3 g3(D4 / 256, NC, B);      // (4, 256, 2) = 2048 blocks
    final_kernel<<<g3, 256, 0, stream>>>(
        x, wgate, rgate, role_w, role_r, prefix, out);
}

// Round 12
// 85.361 us; speedup vs baseline: 2.0841x; 1.4324x over previous
//
#include <hip/hip_runtime.h>
#include <math.h>

// HDCFactMemory:
//   out = x + r_gate[b,t] * K[d] * sign(S[b,t,d]) * sign(x[b,t,d])
//   K[d] = sign(role_write[d])*sign(role_read[d])   (factored, exact)
//   S[b,t,d] = sum_{t'<=t} sign(x[b,t',d]) * w_gate[b,t']
// Sign-determining math in f64 (np-f64 reference; absmax pinned at 0.015625).
//
// R12 = R9 (88.8us proven) + ONE change: K2b serial prefix (32 blocks,
// 128-long chain, ~15us) -> sectioned parallel prefix (256 blocks x 256thr,
// 8 thr/col, 16-chunk sections, shfl scan, ~4us). K12/K3 byte-identical to R9.

#define T_LEN 4096
#define D_LEN 4096
#define TC 32              // rows per chunk
#define NC (T_LEN / TC)    // 128 chunks per batch
#define D4 (D_LEN / 4)     // 1024 float4 (and code-bytes) per row
#define NSEC 8             // prefix sections per column
#define SEC (NC / NSEC)    // 16 chunks per section

typedef float nfloat4 __attribute__((ext_vector_type(4)));

__device__ __forceinline__ float fsgn(float v) {
    return (v > 0.f) ? 1.f : ((v < 0.f) ? -1.f : 0.f);
}
__device__ __forceinline__ double dsgn(double v) {
    return (v > 0.) ? 1. : ((v < 0.) ? -1. : 0.);
}
__device__ __forceinline__ unsigned scode(float v) {   // 0:neg 1:zero 2:pos
    return (v > 0.f) ? 2u : ((v < 0.f) ? 0u : 1u);
}

// ---- K12: per-chunk gates + partials (codes via LDS, no global round-trip)
__global__ __launch_bounds__(1024) void gates_partial_kernel(
    const float* __restrict__ x,
    const float* __restrict__ wg_w, const float* __restrict__ wg_b,
    const float* __restrict__ rg_w, const float* __restrict__ rg_b,
    double* __restrict__ wgate, double* __restrict__ rgate,
    double* __restrict__ partial)
{
    const int c = blockIdx.x;
    const int b = blockIdx.y;
    const int tid = threadIdx.x;

    __shared__ unsigned char codes[TC][D4];   // 32 KB
    __shared__ double wg_s[TC];
    __shared__ double rg_s[TC];

    // ---- phase A: gate dots (32 threads per row) + code pack into LDS ----
    const int r  = tid >> 5;          // row in chunk [0,32)
    const int k0 = tid & 31;          // 32 threads stride the row
    const float4* xr = (const float4*)(x + ((size_t)b * T_LEN + (size_t)c * TC + r) * D_LEN);
    const float4* w4 = (const float4*)wg_w;
    const float4* g4 = (const float4*)rg_w;

    double dw = 0., dg = 0.;
    #pragma unroll 4
    for (int j = 0; j < 32; ++j) {
        const int idx = k0 + j * 32;
        float4 v = xr[idx];
        float4 a = w4[idx];
        float4 g = g4[idx];
        dw += (double)v.x * a.x + (double)v.y * a.y
            + (double)v.z * a.z + (double)v.w * a.w;
        dg += (double)v.x * g.x + (double)v.y * g.y
            + (double)v.z * g.z + (double)v.w * g.w;
        codes[r][idx] = (unsigned char)(scode(v.x) | (scode(v.y) << 2)
                                      | (scode(v.z) << 4) | (scode(v.w) << 6));
    }
    #pragma unroll
    for (int off = 16; off >= 1; off >>= 1) {
        dw += __shfl_down(dw, off, 32);
        dg += __shfl_down(dg, off, 32);
    }
    if (k0 == 0) {
        wg_s[r] = 1. / (1. + exp(-(dw + (double)wg_b[0])));
        rg_s[r] = 1. / (1. + exp(-(dg + (double)rg_b[0])));
    }
    __syncthreads();

    // export gates for K3
    if (tid < TC) {
        const int row = b * T_LEN + c * TC + tid;
        wgate[row] = wg_s[tid];
        rgate[row] = rg_s[tid];
    }

    // ---- phase B: chunk partial per byte-column (thread = one float4 col) --
    double a0 = 0., a1 = 0., a2 = 0., a3 = 0.;
    #pragma unroll 8
    for (int t = 0; t < TC; ++t) {
        unsigned code = codes[t][tid];
        double w = wg_s[t];
        a0 += (double)((int)( code       & 3u) - 1) * w;
        a1 += (double)((int)((code >> 2) & 3u) - 1) * w;
        a2 += (double)((int)((code >> 4) & 3u) - 1) * w;
        a3 += (double)((int)((code >> 6) & 3u) - 1) * w;
    }
    double* rec = partial + ((size_t)(b * NC + c)) * D_LEN + tid * 4;
    rec[0] = a0; rec[1] = a1; rec[2] = a2; rec[3] = a3;
}

// ---- K2b: sectioned parallel exclusive prefix over chunks ----
// 8 threads per column, 16-chunk sections; section sums -> 8-lane shfl
// exclusive scan -> rewalk. 256 blocks x 256 threads (was 32 blocks serial).
__global__ __launch_bounds__(256) void prefix_kernel(
    const double* __restrict__ partial, double* __restrict__ prefix)
{
    const int tid  = threadIdx.x;
    const int colg = tid >> 3;                  // 32 columns per block
    const int sec  = tid & 7;
    const int g    = blockIdx.x * 32 + colg;    // global column in [0, B*4096)
    const int b    = g >> 12;                   // /4096
    const int m    = g & 4095;

    // section sum (independent strided loads, fully pipelined)
    double s = 0.;
    #pragma unroll
    for (int k = 0; k < SEC; ++k) {
        const int cc = sec * SEC + k;
        s += partial[((size_t)(b * NC + cc)) * D_LEN + m];
    }
    // inclusive 8-lane scan, shift for exclusive
    double inc = s;
    #pragma unroll
    for (int off = 1; off < NSEC; off <<= 1) {
        double n = __shfl_up(inc, off, NSEC);
        if (sec >= off) inc += n;
    }
    double run = __shfl_up(inc, 1, NSEC);
    if (sec == 0) run = 0.;
    // rewalk: write exclusive prefix per chunk
    #pragma unroll
    for (int k = 0; k < SEC; ++k) {
        const int cc = sec * SEC + k;
        const size_t idx = ((size_t)(b * NC + cc)) * D_LEN + m;
        double v = partial[idx];
        prefix[idx] = run;
        run += v;
    }
}

// ---- K3: in-chunk sequential f64 rescan + f32 output (NT stores) ----
__global__ __launch_bounds__(256) void final_kernel(
    const float* __restrict__ x,
    const double* __restrict__ wgate, const double* __restrict__ rgate,
    const float* __restrict__ role_w, const float* __restrict__ role_r,
    const double* __restrict__ prefix,
    float* __restrict__ out)
{
    const int b = blockIdx.z;
    const int c = blockIdx.y;
    const int d4 = blockIdx.x * 256 + threadIdx.x;

    __shared__ double wsm[TC];
    __shared__ float rsm[TC];
    if (threadIdx.x < TC) {
        wsm[threadIdx.x] = wgate[b * T_LEN + c * TC + threadIdx.x];
        rsm[threadIdx.x] = (float)rgate[b * T_LEN + c * TC + threadIdx.x];
    }
    __syncthreads();

    float4 rw = ((const float4*)role_w)[d4];
    float4 rr = ((const float4*)role_r)[d4];
    const float kx = fsgn(rw.x) * fsgn(rr.x);
    const float ky = fsgn(rw.y) * fsgn(rr.y);
    const float kz = fsgn(rw.z) * fsgn(rr.z);
    const float kw = fsgn(rw.w) * fsgn(rr.w);

    const double* p = prefix + ((size_t)(b * NC + c)) * D_LEN + d4 * 4;
    double ax = p[0], ay = p[1], az = p[2], aw = p[3];

    const float4* x4 = (const float4*)x;
    nfloat4* o4 = (nfloat4*)out;
    const size_t slab = ((size_t)b * T_LEN + (size_t)c * TC) * D4 + d4;

    #pragma unroll 4
    for (int i = 0; i < TC; ++i) {
        float4 v = x4[slab + (size_t)i * D4];
        double w = wsm[i];
        float rf = rsm[i];
        float sx = fsgn(v.x), sy = fsgn(v.y), sz = fsgn(v.z), sw2 = fsgn(v.w);
        ax += (double)sx * w; ay += (double)sy * w;
        az += (double)sz * w; aw += (double)sw2 * w;
        nfloat4 o;
        o.x = v.x + rf * kx * (float)dsgn(ax) * sx;
        o.y = v.y + rf * ky * (float)dsgn(ay) * sy;
        o.z = v.z + rf * kz * (float)dsgn(az) * sz;
        o.w = v.w + rf * kw * (float)dsgn(aw) * sw2;
        __builtin_nontemporal_store(o, &o4[slab + (size_t)i * D4]);
    }
}

extern "C" void kernel_launch(void* const* d_in, const int* in_sizes, int n_in,
                              void* d_out, int out_size, void* d_ws, size_t ws_size,
                              hipStream_t stream) {
    const float* x      = (const float*)d_in[0];
    const float* role_w = (const float*)d_in[1];
    const float* role_r = (const float*)d_in[2];
    const float* wg_w   = (const float*)d_in[3];
    const float* wg_b   = (const float*)d_in[4];
    const float* rg_w   = (const float*)d_in[5];
    const float* rg_b   = (const float*)d_in[6];
    float* out = (float*)d_out;

    const int B = in_sizes[0] / (T_LEN * D_LEN);   // = 2
    const int BT = B * T_LEN;

    // ws layout (f64): wgate[BT], rgate[BT], partial[B*NC*D], prefix[same]
    double* wgate   = (double*)d_ws;
    double* rgate   = wgate + BT;
    double* partial = rgate + BT;
    double* prefix  = partial + (size_t)B * NC * D_LEN;   // total ~17 MB

    dim3 g12(NC, B);               // (128, 2)
    gates_partial_kernel<<<g12, 1024, 0, stream>>>(
        x, wg_w, wg_b, rg_w, rg_b, wgate, rgate, partial);

    const int ncols = B * D_LEN;   // 8192 columns, 32 per block
    prefix_kernel<<<ncols / 32, 256, 0, stream>>>(partial, prefix);

    dim3 g3(D4 / 256, NC, B);      // (4, 128, 2)
    final_kernel<<<g3, 256, 0, stream>>>(
        x, wgate, rgate, role_w, role_r, prefix, out);
}